// Round 5
// baseline (252.645 us; speedup 1.0000x reference)
//
#include <hip/hip_runtime.h>

typedef unsigned int u32;
typedef unsigned short u16;

typedef short bf16x8 __attribute__((ext_vector_type(8)));
typedef float f32x4 __attribute__((ext_vector_type(4)));

#define GM 2048      // B
#define GN 11008     // O
#define GK 4096      // I
#define NGRP 32      // N = I/G
#define GSZ 128      // G

#define CAST_G(p) ((const __attribute__((address_space(1))) void*)(p))
#define CAST_L(p) ((__attribute__((address_space(3))) void*)(p))
#define BAR() __builtin_amdgcn_s_barrier()
#define SCHED0() __builtin_amdgcn_sched_barrier(0)

__device__ __forceinline__ u16 f2bf(float f) {
    u32 u = __builtin_bit_cast(u32, f);
    u32 r = (u + 0x7FFFu + ((u >> 16) & 1u)) >> 16;
    return (u16)r;
}

// ---------------------------------------------------------------------------
// Kernel 1: rotate x -> rx (bf16).  (unchanged — near roofline)
// ---------------------------------------------------------------------------
__global__ __launch_bounds__(256) void rotate_kernel(
    const float* __restrict__ x, const float* __restrict__ s1,
    const float* __restrict__ s2, u32* __restrict__ rx) {
    int gid  = blockIdx.x * 256 + threadIdx.x;
    int grp  = gid >> 6;
    int lane = gid & 63;

    const float2* xp = (const float2*)(x + (size_t)grp * GSZ);
    float2 xv  = xp[lane];
    float2 s1v = ((const float2*)s1)[lane];
    float2 s2v = ((const float2*)s2)[lane];

    float e0 = xv.x * s1v.x;
    float e1 = xv.y * s1v.y;
    {
        float a = e0 + e1, b = e0 - e1;
        e0 = a; e1 = b;
    }
    #pragma unroll
    for (int hb = 1; hb <= 32; hb <<= 1) {
        float t0 = __shfl_xor(e0, hb, 64);
        float t1 = __shfl_xor(e1, hb, 64);
        bool up = (lane & hb) != 0;
        e0 = up ? (t0 - e0) : (e0 + t0);
        e1 = up ? (t1 - e1) : (e1 + t1);
    }
    const float inv = 0.08838834764831845f;   // 1/sqrt(128)
    u32 lo = f2bf(e0 * s2v.x * inv);
    u32 hi = f2bf(e1 * s2v.y * inv);
    rx[gid] = lo | (hi << 16);
}

// ---------------------------------------------------------------------------
// Kernel 2: dequantize packed 3-bit -> wq bf16 [O][I]. (unchanged)
// ---------------------------------------------------------------------------
__device__ __forceinline__ float cent3(int i) {
    int m3 = (i >= 4) ? (i - 4) : (3 - i);
    float mag = (m3 >= 2) ? ((m3 == 3) ? 2.1519f : 1.3439f)
                          : ((m3 == 1) ? 0.756f  : 0.2451f);
    return (i >= 4) ? mag : -mag;
}

__global__ __launch_bounds__(256) void dequant_kernel(
    const u32* __restrict__ p32, const float* __restrict__ norms,
    u16* __restrict__ wq) {
    int u = blockIdx.x * 256 + threadIdx.x;
    int g_idx = u >> 2;

    float scale = norms[g_idx] * 0.08838834764831845f;

    u32 w0 = p32[(size_t)u * 3 + 0];
    u32 w1 = p32[(size_t)u * 3 + 1];
    u32 w2 = p32[(size_t)u * 3 + 2];

    u32 tri[4];
    if (((w0 | w1 | w2) & 0xFFFFFF00u) == 0u) {
        const u32* pi = p32 + (size_t)u * 12;
        u32 b[12];
        #pragma unroll
        for (int k = 0; k < 12; ++k) b[k] = pi[k];
        #pragma unroll
        for (int t = 0; t < 4; ++t)
            tri[t] = b[3*t] | (b[3*t+1] << 8) | (b[3*t+2] << 16);
    } else {
        tri[0] = w0 & 0xFFFFFFu;
        tri[1] = (w0 >> 24) | ((w1 & 0xFFFFu) << 8);
        tri[2] = (w1 >> 16) | ((w2 & 0xFFu) << 16);
        tri[3] = w2 >> 8;
    }

    u32 ow[16];
    #pragma unroll
    for (int t = 0; t < 4; ++t) {
        u32 v = tri[t];
        #pragma unroll
        for (int k = 0; k < 4; ++k) {
            int i0 = (int)((v >> (6*k))     & 7u);
            int i1 = (int)((v >> (6*k + 3)) & 7u);
            u32 lo = f2bf(cent3(i0) * scale);
            u32 hi = f2bf(cent3(i1) * scale);
            ow[t*4 + k] = lo | (hi << 16);
        }
    }
    u32* op = (u32*)(wq + (size_t)u * 32);
    #pragma unroll
    for (int k = 0; k < 16; ++k) op[k] = ow[k];
}

// ---------------------------------------------------------------------------
// Kernel 2b: zero the split-K tail region C[:, 8192:11008) (23 MB).
// ---------------------------------------------------------------------------
__global__ __launch_bounds__(256) void zero_tail_kernel(float* __restrict__ C) {
    int idx = blockIdx.x * 256 + threadIdx.x;       // < 2048*704
    int row = idx / 704;
    int c4  = idx - row * 704;
    f32x4* p = (f32x4*)(C + (size_t)row * GN + 8192 + c4 * 4);
    *p = f32x4{0.f, 0.f, 0.f, 0.f};
}

// ---------------------------------------------------------------------------
// Kernel 3: GEMM C = A[M][K]*B[N][K]^T — 256x256 tile, BK=64, 8 waves,
// hybrid split-K grid (432 blocks):
//   bid <  256: full-K tile tau=bid          (nT=64, plain stores)
//   bid >= 256: half-K tile tau=256+(h>>1), khalf=h&1 (nT=32, atomicAdd)
// Tail tiles are exactly n0 >= 32*256 = 8192 — region pre-zeroed.
// ktile schedule identical to round-2 (verified): 4 phases/K-tile, 2-deep
// 128 KiB LDS, counted vmcnt(6), T2 both-sides XOR swizzle, T5 setprio.
// ---------------------------------------------------------------------------
__device__ __forceinline__ void stage_half(const u16* g, char* ldst, int rowOff, int tt) {
    __builtin_amdgcn_global_load_lds(CAST_G(g + (size_t)rowOff * GK + tt * 64),
                                     CAST_L(ldst), 16, 0, 0);
    __builtin_amdgcn_global_load_lds(CAST_G(g + (size_t)(rowOff + 64) * GK + tt * 64),
                                     CAST_L(ldst + 8192), 16, 0, 0);
}

template<int BUF>
__device__ __forceinline__ void ktile(int t, int nT, char* lds,
                                      const u16* gA, const u16* gB,
                                      int sB, int aBase, int bBase, int sw0, int sw1,
                                      f32x4 (&acc)[8][4]) {
    const int AB  = BUF * 32768;               // A region, this buffer
    const int BB  = 65536 + BUF * 32768;       // B region, this buffer
    const int BBo = 65536 + (BUF ^ 1) * 32768; // B region, other buffer

    bf16x8 aF[4][2], b0F[2][2], b1F[2][2];
    bool s1 = (t < nT - 1), s2 = (t < nT - 2);

    // ---- phase 1: quadrant (mh0, nh0)
    #pragma unroll
    for (int mj = 0; mj < 4; ++mj) {
        aF[mj][0] = *(const bf16x8*)(lds + AB + aBase + mj * 4096 + sw0);
        aF[mj][1] = *(const bf16x8*)(lds + AB + aBase + mj * 4096 + sw1);
    }
    #pragma unroll
    for (int nj = 0; nj < 2; ++nj) {
        b0F[nj][0] = *(const bf16x8*)(lds + BB + bBase + nj * 8192 + sw0);
        b0F[nj][1] = *(const bf16x8*)(lds + BB + bBase + nj * 8192 + sw1);
    }
    if (s1) stage_half(gB, lds + BBo + 16384 + sB, 128, t + 1);   // (t+1) B1
    BAR(); SCHED0();
    __builtin_amdgcn_s_setprio(1);
    #pragma unroll
    for (int mj = 0; mj < 4; ++mj)
        #pragma unroll
        for (int nj = 0; nj < 2; ++nj)
            #pragma unroll
            for (int kk = 0; kk < 2; ++kk)
                acc[mj][nj] = __builtin_amdgcn_mfma_f32_16x16x32_bf16(
                    aF[mj][kk], b0F[nj][kk], acc[mj][nj], 0, 0, 0);
    __builtin_amdgcn_s_setprio(0);
    BAR();

    // ---- phase 2: (mh0, nh1)
    #pragma unroll
    for (int nj = 0; nj < 2; ++nj) {
        b1F[nj][0] = *(const bf16x8*)(lds + BB + 16384 + bBase + nj * 8192 + sw0);
        b1F[nj][1] = *(const bf16x8*)(lds + BB + 16384 + bBase + nj * 8192 + sw1);
    }
    if (s2) stage_half(gA, lds + AB + sB, 0, t + 2);              // (t+2) A0
    BAR(); SCHED0();
    __builtin_amdgcn_s_setprio(1);
    #pragma unroll
    for (int mj = 0; mj < 4; ++mj)
        #pragma unroll
        for (int nj = 0; nj < 2; ++nj)
            #pragma unroll
            for (int kk = 0; kk < 2; ++kk)
                acc[mj][2 + nj] = __builtin_amdgcn_mfma_f32_16x16x32_bf16(
                    aF[mj][kk], b1F[nj][kk], acc[mj][2 + nj], 0, 0, 0);
    __builtin_amdgcn_s_setprio(0);
    BAR();

    // ---- phase 3: (mh1, nh0)
    #pragma unroll
    for (int mj = 0; mj < 4; ++mj) {
        aF[mj][0] = *(const bf16x8*)(lds + AB + 16384 + aBase + mj * 4096 + sw0);
        aF[mj][1] = *(const bf16x8*)(lds + AB + 16384 + aBase + mj * 4096 + sw1);
    }
    if (s2) stage_half(gB, lds + BB + sB, 0, t + 2);              // (t+2) B0
    BAR(); SCHED0();
    __builtin_amdgcn_s_setprio(1);
    #pragma unroll
    for (int mj = 0; mj < 4; ++mj)
        #pragma unroll
        for (int nj = 0; nj < 2; ++nj)
            #pragma unroll
            for (int kk = 0; kk < 2; ++kk)
                acc[4 + mj][nj] = __builtin_amdgcn_mfma_f32_16x16x32_bf16(
                    aF[mj][kk], b0F[nj][kk], acc[4 + mj][nj], 0, 0, 0);
    __builtin_amdgcn_s_setprio(0);
    BAR();

    // ---- phase 4: (mh1, nh1)
    if (s2) stage_half(gA, lds + AB + 16384 + sB, 128, t + 2);    // (t+2) A1
    BAR(); SCHED0();
    __builtin_amdgcn_s_setprio(1);
    #pragma unroll
    for (int mj = 0; mj < 4; ++mj)
        #pragma unroll
        for (int nj = 0; nj < 2; ++nj)
            #pragma unroll
            for (int kk = 0; kk < 2; ++kk)
                acc[4 + mj][2 + nj] = __builtin_amdgcn_mfma_f32_16x16x32_bf16(
                    aF[mj][kk], b1F[nj][kk], acc[4 + mj][2 + nj], 0, 0, 0);
    __builtin_amdgcn_s_setprio(0);
    if (s2) { asm volatile("s_waitcnt vmcnt(6)" ::: "memory"); }
    else    { asm volatile("s_waitcnt vmcnt(0)" ::: "memory"); }
    BAR();
}

__global__ __launch_bounds__(512, 1) void gemm256h_kernel(
    const u16* __restrict__ A, const u16* __restrict__ Bw,
    float* __restrict__ C) {
    extern __shared__ char lds[];
    int tid  = threadIdx.x;
    int lane = tid & 63;
    int wv   = tid >> 6;
    int wr   = wv >> 2;      // 0..1
    int wc   = wv & 3;       // 0..3

    int bid = blockIdx.x;
    bool half = (bid >= 256);
    int tau, khalf, nT;
    if (!half) { tau = bid; khalf = 0; nT = 64; }
    else       { int h = bid - 256; tau = 256 + (h >> 1); khalf = h & 1; nT = 32; }
    int m0 = (tau & 7) * 256;        // XCD x owns M-panel x (full blocks)
    int n0 = (tau >> 3) * 256;       // halves: n0 >= 8192 (pre-zeroed region)

    // staging: per-thread pre-swizzled global source (linear LDS dest)
    int srow = tid >> 3;                       // 0..63
    int c16  = (tid & 7) ^ (srow & 7);
    const u16* gA = A  + (size_t)(m0 + srow) * GK + khalf * 2048 + c16 * 8;
    const u16* gB = Bw + (size_t)(n0 + srow) * GK + khalf * 2048 + c16 * 8;
    int sB = wv * 1024;

    // ds_read bases (byte), swizzled 16B slot: slot ^ (row&7); row&7 == lane&7
    int aBase = (wr * 16 + (lane & 15)) * 128;
    int bBase = (wc * 16 + (lane & 15)) * 128;
    int sw0 = (((lane >> 4))     ^ (lane & 7)) << 4;   // kk=0
    int sw1 = (((lane >> 4) + 4) ^ (lane & 7)) << 4;   // kk=32

    f32x4 acc[8][4] = {};

    // prologue: tile0 {A0,B0,A1,B1} + tile1 {A0,B0,A1}; vmcnt(6) -> tile0 done
    stage_half(gA, lds + sB,                 0,   0);
    stage_half(gB, lds + 65536 + sB,         0,   0);
    stage_half(gA, lds + 16384 + sB,         128, 0);
    stage_half(gB, lds + 65536 + 16384 + sB, 128, 0);
    stage_half(gA, lds + 32768 + sB,         0,   1);
    stage_half(gB, lds + 65536 + 32768 + sB, 0,   1);
    stage_half(gA, lds + 32768 + 16384 + sB, 128, 1);
    asm volatile("s_waitcnt vmcnt(6)" ::: "memory");
    BAR();

    for (int tt = 0; tt < nT; tt += 2) {
        ktile<0>(tt,     nT, lds, gA, gB, sB, aBase, bBase, sw0, sw1, acc);
        ktile<1>(tt + 1, nT, lds, gA, gB, sB, aBase, bBase, sw0, sw1, acc);
    }

    // epilogue: C/D layout col=lane&15, row=(lane>>4)*4+j
    int cr = (lane >> 4) * 4;
    int cc = lane & 15;
    #pragma unroll
    for (int mh = 0; mh < 2; ++mh)
        #pragma unroll
        for (int mj = 0; mj < 4; ++mj)
            #pragma unroll
            for (int nh = 0; nh < 2; ++nh)
                #pragma unroll
                for (int nj = 0; nj < 2; ++nj) {
                    float* cp = C + (size_t)(m0 + mh * 128 + wr * 16 + mj * 32 + cr) * GN
                                  + (n0 + nh * 128 + wc * 16 + nj * 64 + cc);
                    f32x4 v = acc[mh * 4 + mj][nh * 2 + nj];
                    if (!half) {
                        #pragma unroll
                        for (int j = 0; j < 4; ++j)
                            cp[(size_t)j * GN] = v[j];
                    } else {
                        #pragma unroll
                        for (int j = 0; j < 4; ++j)
                            atomicAdd(&cp[(size_t)j * GN], v[j]);
                    }
                }
}

// ---------------------------------------------------------------------------
extern "C" void kernel_launch(void* const* d_in, const int* in_sizes, int n_in,
                              void* d_out, int out_size, void* d_ws, size_t ws_size,
                              hipStream_t stream) {
    const float* x      = (const float*)d_in[0];
    const void*  packed = d_in[1];
    const float* norms  = (const float*)d_in[2];
    const float* s1     = (const float*)d_in[4];
    const float* s2     = (const float*)d_in[5];
    float* out          = (float*)d_out;

    size_t rx_bytes = (size_t)GM * GK * 2;
    size_t wq_bytes = (size_t)GN * GK * 2;
    if (ws_size < rx_bytes + wq_bytes) return;

    u16* rx = (u16*)d_ws;
    u16* wq = rx + (size_t)GM * GK;

    rotate_kernel<<<dim3((GM * NGRP * 64) / 256), dim3(256), 0, stream>>>(
        x, s1, s2, (u32*)rx);

    dequant_kernel<<<dim3((GN * NGRP * 4) / 256), dim3(256), 0, stream>>>(
        (const u32*)packed, norms, wq);

    // zero the split-K tail region C[:, 8192:) before the GEMM accumulates
    zero_tail_kernel<<<dim3((GM * 704) / 256), dim3(256), 0, stream>>>(out);

    hipFuncSetAttribute((const void*)gemm256h_kernel,
                        hipFuncAttributeMaxDynamicSharedMemorySize, 131072);
    gemm256h_kernel<<<dim3(432), dim3(512), 131072, stream>>>(rx, wq, out);
}

// Round 6
// 227.384 us; speedup vs baseline: 1.1111x; 1.1111x over previous
//
#include <hip/hip_runtime.h>

typedef unsigned int u32;
typedef unsigned short u16;

typedef short bf16x8 __attribute__((ext_vector_type(8)));
typedef float f32x4 __attribute__((ext_vector_type(4)));

#define GM 2048      // B
#define GN 11008     // O
#define GK 4096      // I
#define NGRP 32      // N = I/G
#define GSZ 128      // G

#define CAST_G(p) ((const __attribute__((address_space(1))) void*)(p))
#define CAST_L(p) ((__attribute__((address_space(3))) void*)(p))
#define BAR() __builtin_amdgcn_s_barrier()
#define SCHED0() __builtin_amdgcn_sched_barrier(0)

__device__ __forceinline__ u16 f2bf(float f) {
    u32 u = __builtin_bit_cast(u32, f);
    u32 r = (u + 0x7FFFu + ((u >> 16) & 1u)) >> 16;
    return (u16)r;
}

// ---------------------------------------------------------------------------
// Kernel 1: rotate x -> rx (bf16).  (unchanged — near roofline)
// ---------------------------------------------------------------------------
__global__ __launch_bounds__(256) void rotate_kernel(
    const float* __restrict__ x, const float* __restrict__ s1,
    const float* __restrict__ s2, u32* __restrict__ rx) {
    int gid  = blockIdx.x * 256 + threadIdx.x;
    int grp  = gid >> 6;
    int lane = gid & 63;

    const float2* xp = (const float2*)(x + (size_t)grp * GSZ);
    float2 xv  = xp[lane];
    float2 s1v = ((const float2*)s1)[lane];
    float2 s2v = ((const float2*)s2)[lane];

    float e0 = xv.x * s1v.x;
    float e1 = xv.y * s1v.y;
    {
        float a = e0 + e1, b = e0 - e1;
        e0 = a; e1 = b;
    }
    #pragma unroll
    for (int hb = 1; hb <= 32; hb <<= 1) {
        float t0 = __shfl_xor(e0, hb, 64);
        float t1 = __shfl_xor(e1, hb, 64);
        bool up = (lane & hb) != 0;
        e0 = up ? (t0 - e0) : (e0 + t0);
        e1 = up ? (t1 - e1) : (e1 + t1);
    }
    const float inv = 0.08838834764831845f;   // 1/sqrt(128)
    u32 lo = f2bf(e0 * s2v.x * inv);
    u32 hi = f2bf(e1 * s2v.y * inv);
    rx[gid] = lo | (hi << 16);
}

// ---------------------------------------------------------------------------
// Kernel 2: dequantize packed 3-bit -> wq bf16 [O][I]. (unchanged)
// ---------------------------------------------------------------------------
__device__ __forceinline__ float cent3(int i) {
    int m3 = (i >= 4) ? (i - 4) : (3 - i);
    float mag = (m3 >= 2) ? ((m3 == 3) ? 2.1519f : 1.3439f)
                          : ((m3 == 1) ? 0.756f  : 0.2451f);
    return (i >= 4) ? mag : -mag;
}

__global__ __launch_bounds__(256) void dequant_kernel(
    const u32* __restrict__ p32, const float* __restrict__ norms,
    u16* __restrict__ wq) {
    int u = blockIdx.x * 256 + threadIdx.x;
    int g_idx = u >> 2;

    float scale = norms[g_idx] * 0.08838834764831845f;

    u32 w0 = p32[(size_t)u * 3 + 0];
    u32 w1 = p32[(size_t)u * 3 + 1];
    u32 w2 = p32[(size_t)u * 3 + 2];

    u32 tri[4];
    if (((w0 | w1 | w2) & 0xFFFFFF00u) == 0u) {
        const u32* pi = p32 + (size_t)u * 12;
        u32 b[12];
        #pragma unroll
        for (int k = 0; k < 12; ++k) b[k] = pi[k];
        #pragma unroll
        for (int t = 0; t < 4; ++t)
            tri[t] = b[3*t] | (b[3*t+1] << 8) | (b[3*t+2] << 16);
    } else {
        tri[0] = w0 & 0xFFFFFFu;
        tri[1] = (w0 >> 24) | ((w1 & 0xFFFFu) << 8);
        tri[2] = (w1 >> 16) | ((w2 & 0xFFu) << 16);
        tri[3] = w2 >> 8;
    }

    u32 ow[16];
    #pragma unroll
    for (int t = 0; t < 4; ++t) {
        u32 v = tri[t];
        #pragma unroll
        for (int k = 0; k < 4; ++k) {
            int i0 = (int)((v >> (6*k))     & 7u);
            int i1 = (int)((v >> (6*k + 3)) & 7u);
            u32 lo = f2bf(cent3(i0) * scale);
            u32 hi = f2bf(cent3(i1) * scale);
            ow[t*4 + k] = lo | (hi << 16);
        }
    }
    u32* op = (u32*)(wq + (size_t)u * 32);
    #pragma unroll
    for (int k = 0; k < 16; ++k) op[k] = ow[k];
}

// ---------------------------------------------------------------------------
// Shared: async half-tile staging (64 rows x 64 cols bf16)
// ---------------------------------------------------------------------------
__device__ __forceinline__ void stage_half(const u16* g, char* ldst, int rowOff, int tt) {
    __builtin_amdgcn_global_load_lds(CAST_G(g + (size_t)rowOff * GK + tt * 64),
                                     CAST_L(ldst), 16, 0, 0);
    __builtin_amdgcn_global_load_lds(CAST_G(g + (size_t)(rowOff + 64) * GK + tt * 64),
                                     CAST_L(ldst + 8192), 16, 0, 0);
}

// ---------------------------------------------------------------------------
// Kernel 3a: 256x256-tile GEMM (dispatch 1, grid 256 = one perfect round).
// Verbatim round-2 ktile: 4 phases/K-tile, 2-deep 128 KiB LDS, counted
// vmcnt(6), T2 both-sides XOR swizzle, T5 setprio, XCD-pinned A panel.
// ---------------------------------------------------------------------------
template<int BUF>
__device__ __forceinline__ void ktile4(int t, char* lds,
                                       const u16* gA, const u16* gB,
                                       int sB, int aBase, int bBase, int sw0, int sw1,
                                       f32x4 (&acc)[8][4]) {
    const int AB  = BUF * 32768;
    const int BB  = 65536 + BUF * 32768;
    const int BBo = 65536 + (BUF ^ 1) * 32768;

    bf16x8 aF[4][2], b0F[2][2], b1F[2][2];
    bool s1 = (t < 63), s2 = (t < 62);

    // ---- phase 1: quadrant (mh0, nh0)
    #pragma unroll
    for (int mj = 0; mj < 4; ++mj) {
        aF[mj][0] = *(const bf16x8*)(lds + AB + aBase + mj * 4096 + sw0);
        aF[mj][1] = *(const bf16x8*)(lds + AB + aBase + mj * 4096 + sw1);
    }
    #pragma unroll
    for (int nj = 0; nj < 2; ++nj) {
        b0F[nj][0] = *(const bf16x8*)(lds + BB + bBase + nj * 8192 + sw0);
        b0F[nj][1] = *(const bf16x8*)(lds + BB + bBase + nj * 8192 + sw1);
    }
    if (s1) stage_half(gB, lds + BBo + 16384 + sB, 128, t + 1);   // (t+1) B1
    BAR(); SCHED0();
    __builtin_amdgcn_s_setprio(1);
    #pragma unroll
    for (int mj = 0; mj < 4; ++mj)
        #pragma unroll
        for (int nj = 0; nj < 2; ++nj)
            #pragma unroll
            for (int kk = 0; kk < 2; ++kk)
                acc[mj][nj] = __builtin_amdgcn_mfma_f32_16x16x32_bf16(
                    aF[mj][kk], b0F[nj][kk], acc[mj][nj], 0, 0, 0);
    __builtin_amdgcn_s_setprio(0);
    BAR();

    // ---- phase 2: (mh0, nh1)
    #pragma unroll
    for (int nj = 0; nj < 2; ++nj) {
        b1F[nj][0] = *(const bf16x8*)(lds + BB + 16384 + bBase + nj * 8192 + sw0);
        b1F[nj][1] = *(const bf16x8*)(lds + BB + 16384 + bBase + nj * 8192 + sw1);
    }
    if (s2) stage_half(gA, lds + AB + sB, 0, t + 2);              // (t+2) A0
    BAR(); SCHED0();
    __builtin_amdgcn_s_setprio(1);
    #pragma unroll
    for (int mj = 0; mj < 4; ++mj)
        #pragma unroll
        for (int nj = 0; nj < 2; ++nj)
            #pragma unroll
            for (int kk = 0; kk < 2; ++kk)
                acc[mj][2 + nj] = __builtin_amdgcn_mfma_f32_16x16x32_bf16(
                    aF[mj][kk], b1F[nj][kk], acc[mj][2 + nj], 0, 0, 0);
    __builtin_amdgcn_s_setprio(0);
    BAR();

    // ---- phase 3: (mh1, nh0)
    #pragma unroll
    for (int mj = 0; mj < 4; ++mj) {
        aF[mj][0] = *(const bf16x8*)(lds + AB + 16384 + aBase + mj * 4096 + sw0);
        aF[mj][1] = *(const bf16x8*)(lds + AB + 16384 + aBase + mj * 4096 + sw1);
    }
    if (s2) stage_half(gB, lds + BB + sB, 0, t + 2);              // (t+2) B0
    BAR(); SCHED0();
    __builtin_amdgcn_s_setprio(1);
    #pragma unroll
    for (int mj = 0; mj < 4; ++mj)
        #pragma unroll
        for (int nj = 0; nj < 2; ++nj)
            #pragma unroll
            for (int kk = 0; kk < 2; ++kk)
                acc[4 + mj][nj] = __builtin_amdgcn_mfma_f32_16x16x32_bf16(
                    aF[mj][kk], b0F[nj][kk], acc[4 + mj][nj], 0, 0, 0);
    __builtin_amdgcn_s_setprio(0);
    BAR();

    // ---- phase 4: (mh1, nh1)
    if (s2) stage_half(gA, lds + AB + 16384 + sB, 128, t + 2);    // (t+2) A1
    BAR(); SCHED0();
    __builtin_amdgcn_s_setprio(1);
    #pragma unroll
    for (int mj = 0; mj < 4; ++mj)
        #pragma unroll
        for (int nj = 0; nj < 2; ++nj)
            #pragma unroll
            for (int kk = 0; kk < 2; ++kk)
                acc[4 + mj][2 + nj] = __builtin_amdgcn_mfma_f32_16x16x32_bf16(
                    aF[mj][kk], b1F[nj][kk], acc[4 + mj][2 + nj], 0, 0, 0);
    __builtin_amdgcn_s_setprio(0);
    if (s2) { asm volatile("s_waitcnt vmcnt(6)" ::: "memory"); }
    else    { asm volatile("s_waitcnt vmcnt(0)" ::: "memory"); }
    BAR();
}

__global__ __launch_bounds__(512, 1) void gemm256_kernel(
    const u16* __restrict__ A, const u16* __restrict__ Bw,
    float* __restrict__ C) {
    extern __shared__ char lds[];
    int tid  = threadIdx.x;
    int lane = tid & 63;
    int wv   = tid >> 6;
    int wr   = wv >> 2;      // 0..1
    int wc   = wv & 3;       // 0..3

    int tau = blockIdx.x;            // 0..255: n-tiles 0..31, all m
    int m0 = (tau & 7) * 256;        // XCD x owns A panel x (L2-resident)
    int n0 = (tau >> 3) * 256;

    int srow = tid >> 3;                       // 0..63
    int c16  = (tid & 7) ^ (srow & 7);
    const u16* gA = A  + (size_t)(m0 + srow) * GK + c16 * 8;
    const u16* gB = Bw + (size_t)(n0 + srow) * GK + c16 * 8;
    int sB = wv * 1024;

    int aBase = (wr * 16 + (lane & 15)) * 128;
    int bBase = (wc * 16 + (lane & 15)) * 128;
    int sw0 = (((lane >> 4))     ^ (lane & 7)) << 4;   // kk=0
    int sw1 = (((lane >> 4) + 4) ^ (lane & 7)) << 4;   // kk=32

    f32x4 acc[8][4] = {};

    stage_half(gA, lds + sB,                 0,   0);
    stage_half(gB, lds + 65536 + sB,         0,   0);
    stage_half(gA, lds + 16384 + sB,         128, 0);
    stage_half(gB, lds + 65536 + 16384 + sB, 128, 0);
    stage_half(gA, lds + 32768 + sB,         0,   1);
    stage_half(gB, lds + 65536 + 32768 + sB, 0,   1);
    stage_half(gA, lds + 32768 + 16384 + sB, 128, 1);
    asm volatile("s_waitcnt vmcnt(6)" ::: "memory");
    BAR();

    for (int tt = 0; tt < 64; tt += 2) {
        ktile4<0>(tt,     lds, gA, gB, sB, aBase, bBase, sw0, sw1, acc);
        ktile4<1>(tt + 1, lds, gA, gB, sB, aBase, bBase, sw0, sw1, acc);
    }

    int cr = (lane >> 4) * 4;
    int cc = lane & 15;
    #pragma unroll
    for (int mh = 0; mh < 2; ++mh)
        #pragma unroll
        for (int mj = 0; mj < 4; ++mj)
            #pragma unroll
            for (int nh = 0; nh < 2; ++nh)
                #pragma unroll
                for (int nj = 0; nj < 2; ++nj) {
                    float* cp = C + (size_t)(m0 + mh * 128 + wr * 16 + mj * 32 + cr) * GN
                                  + (n0 + nh * 128 + wc * 16 + nj * 64 + cc);
                    #pragma unroll
                    for (int j = 0; j < 4; ++j)
                        cp[(size_t)j * GN] = acc[mh * 4 + mj][nh * 2 + nj][j];
                }
}

// ---------------------------------------------------------------------------
// Kernel 3b: tail GEMM (dispatch 2, grid 176): n-tiles 32..42 split-M into
// 128x256 full-K blocks, plain stores. Verbatim round-4 3-deep ktile
// (144 KiB LDS, vmcnt(6), 2 phases/K-tile).
// ---------------------------------------------------------------------------
template<int BUF>
__device__ __forceinline__ void ktile2(int t, char* lds,
                                       const u16* gA, const u16* gB,
                                       int sB, int aBase, int bBase, int sw0, int sw1,
                                       f32x4 (&acc)[4][4]) {
    const int AB  = BUF * 16384;
    const int BB  = 49152 + BUF * 32768;
    const int NB  = (BUF + 2 >= 3) ? (BUF - 1) : (BUF + 2);
    const int ABn = NB * 16384;
    const int BBn = 49152 + NB * 32768;

    bf16x8 aF[4][2], bF[2][2];
    bool s2 = (t < 62);

    // ---- phase 1: nj = 0,1
    #pragma unroll
    for (int mj = 0; mj < 4; ++mj) {
        aF[mj][0] = *(const bf16x8*)(lds + AB + aBase + mj * 4096 + sw0);
        aF[mj][1] = *(const bf16x8*)(lds + AB + aBase + mj * 4096 + sw1);
    }
    #pragma unroll
    for (int nj = 0; nj < 2; ++nj) {
        bF[nj][0] = *(const bf16x8*)(lds + BB + bBase + nj * 8192 + sw0);
        bF[nj][1] = *(const bf16x8*)(lds + BB + bBase + nj * 8192 + sw1);
    }
    if (s2) {
        stage_half(gA, lds + ABn + sB, 0, t + 2);                 // A(t+2)
        stage_half(gB, lds + BBn + sB, 0, t + 2);                 // B0(t+2)
    }
    BAR(); SCHED0();
    __builtin_amdgcn_s_setprio(1);
    #pragma unroll
    for (int mj = 0; mj < 4; ++mj)
        #pragma unroll
        for (int nj = 0; nj < 2; ++nj)
            #pragma unroll
            for (int kk = 0; kk < 2; ++kk)
                acc[mj][nj] = __builtin_amdgcn_mfma_f32_16x16x32_bf16(
                    aF[mj][kk], bF[nj][kk], acc[mj][nj], 0, 0, 0);
    __builtin_amdgcn_s_setprio(0);
    BAR();

    // ---- phase 2: nj = 2,3
    #pragma unroll
    for (int nj = 0; nj < 2; ++nj) {
        bF[nj][0] = *(const bf16x8*)(lds + BB + 16384 + bBase + nj * 8192 + sw0);
        bF[nj][1] = *(const bf16x8*)(lds + BB + 16384 + bBase + nj * 8192 + sw1);
    }
    if (s2) stage_half(gB, lds + BBn + 16384 + sB, 128, t + 2);   // B1(t+2)
    BAR(); SCHED0();
    __builtin_amdgcn_s_setprio(1);
    #pragma unroll
    for (int mj = 0; mj < 4; ++mj)
        #pragma unroll
        for (int nj = 0; nj < 2; ++nj)
            #pragma unroll
            for (int kk = 0; kk < 2; ++kk)
                acc[mj][2 + nj] = __builtin_amdgcn_mfma_f32_16x16x32_bf16(
                    aF[mj][kk], bF[nj][kk], acc[mj][2 + nj], 0, 0, 0);
    __builtin_amdgcn_s_setprio(0);
    if (s2) { asm volatile("s_waitcnt vmcnt(6)" ::: "memory"); }
    else    { asm volatile("s_waitcnt vmcnt(0)" ::: "memory"); }
    BAR();
}

__global__ __launch_bounds__(512, 1) void gemm_tail_kernel(
    const u16* __restrict__ A, const u16* __restrict__ Bw,
    float* __restrict__ C) {
    extern __shared__ char lds[];
    int tid  = threadIdx.x;
    int lane = tid & 63;
    int wv   = tid >> 6;
    int wr   = wv >> 2;      // 0..1
    int wc   = wv & 3;       // 0..3

    // 176 blocks = 11 n-tiles (32..42) x 16 m-halves; XCD-chunked bijective
    int bid = blockIdx.x;
    int swz = (bid & 7) * 22 + (bid >> 3);     // 176 = 8 * 22
    int nt  = swz >> 4;                        // 0..10
    int mh  = swz & 15;                        // 0..15
    int m0  = mh * 128;
    int n0  = 8192 + nt * 256;

    int srow = tid >> 3;
    int c16  = (tid & 7) ^ (srow & 7);
    const u16* gA = A  + (size_t)(m0 + srow) * GK + c16 * 8;
    const u16* gB = Bw + (size_t)(n0 + srow) * GK + c16 * 8;
    int sB = wv * 1024;

    int aBase = (wr * 16 + (lane & 15)) * 128;
    int bBase = (wc * 16 + (lane & 15)) * 128;
    int sw0 = (((lane >> 4))     ^ (lane & 7)) << 4;
    int sw1 = (((lane >> 4) + 4) ^ (lane & 7)) << 4;

    f32x4 acc[4][4] = {};

    stage_half(gA, lds + sB,                 0,   0);
    stage_half(gB, lds + 49152 + sB,         0,   0);
    stage_half(gB, lds + 49152 + 16384 + sB, 128, 0);
    stage_half(gA, lds + 16384 + sB,         0,   1);
    stage_half(gB, lds + 81920 + sB,         0,   1);
    stage_half(gB, lds + 81920 + 16384 + sB, 128, 1);
    asm volatile("s_waitcnt vmcnt(6)" ::: "memory");
    BAR();

    for (int tt = 0; tt < 63; tt += 3) {
        ktile2<0>(tt,     lds, gA, gB, sB, aBase, bBase, sw0, sw1, acc);
        ktile2<1>(tt + 1, lds, gA, gB, sB, aBase, bBase, sw0, sw1, acc);
        ktile2<2>(tt + 2, lds, gA, gB, sB, aBase, bBase, sw0, sw1, acc);
    }
    ktile2<0>(63, lds, gA, gB, sB, aBase, bBase, sw0, sw1, acc);

    int cr = (lane >> 4) * 4;
    int cc = lane & 15;
    #pragma unroll
    for (int mj = 0; mj < 4; ++mj)
        #pragma unroll
        for (int nj = 0; nj < 4; ++nj) {
            float* cp = C + (size_t)(m0 + wr * 16 + mj * 32 + cr) * GN
                          + (n0 + wc * 16 + nj * 64 + cc);
            #pragma unroll
            for (int j = 0; j < 4; ++j)
                cp[(size_t)j * GN] = acc[mj][nj][j];
        }
}

// ---------------------------------------------------------------------------
extern "C" void kernel_launch(void* const* d_in, const int* in_sizes, int n_in,
                              void* d_out, int out_size, void* d_ws, size_t ws_size,
                              hipStream_t stream) {
    const float* x      = (const float*)d_in[0];
    const void*  packed = d_in[1];
    const float* norms  = (const float*)d_in[2];
    const float* s1     = (const float*)d_in[4];
    const float* s2     = (const float*)d_in[5];
    float* out          = (float*)d_out;

    size_t rx_bytes = (size_t)GM * GK * 2;
    size_t wq_bytes = (size_t)GN * GK * 2;
    if (ws_size < rx_bytes + wq_bytes) return;

    u16* rx = (u16*)d_ws;
    u16* wq = rx + (size_t)GM * GK;

    rotate_kernel<<<dim3((GM * NGRP * 64) / 256), dim3(256), 0, stream>>>(
        x, s1, s2, (u32*)rx);

    dequant_kernel<<<dim3((GN * NGRP * 4) / 256), dim3(256), 0, stream>>>(
        (const u32*)packed, norms, wq);

    hipFuncSetAttribute((const void*)gemm256_kernel,
                        hipFuncAttributeMaxDynamicSharedMemorySize, 131072);
    hipFuncSetAttribute((const void*)gemm_tail_kernel,
                        hipFuncAttributeMaxDynamicSharedMemorySize, 147456);

    // dispatch 1: one perfect round of 256 x (256x256) tiles, n < 8192
    gemm256_kernel<<<dim3(256), dim3(512), 131072, stream>>>(rx, wq, out);
    // dispatch 2: tail n in [8192, 11008) as 176 x (128x256) full-K blocks
    gemm_tail_kernel<<<dim3(176), dim3(512), 147456, stream>>>(rx, wq, out);
}

// Round 7
// 219.549 us; speedup vs baseline: 1.1507x; 1.0357x over previous
//
#include <hip/hip_runtime.h>

typedef unsigned int u32;
typedef unsigned short u16;

typedef short bf16x8 __attribute__((ext_vector_type(8)));
typedef float f32x4 __attribute__((ext_vector_type(4)));

#define GM 2048      // B
#define GN 11008     // O
#define GK 4096      // I
#define NGRP 32      // N = I/G
#define GSZ 128      // G

#define CAST_G(p) ((const __attribute__((address_space(1))) void*)(p))
#define CAST_L(p) ((__attribute__((address_space(3))) void*)(p))
#define BAR() __builtin_amdgcn_s_barrier()
#define SCHED0() __builtin_amdgcn_sched_barrier(0)

__device__ __forceinline__ u16 f2bf(float f) {
    u32 u = __builtin_bit_cast(u32, f);
    u32 r = (u + 0x7FFFu + ((u >> 16) & 1u)) >> 16;
    return (u16)r;
}

// ---------------------------------------------------------------------------
// Kernel 1: rotate x -> rx (bf16).  (unchanged — near roofline)
// ---------------------------------------------------------------------------
__global__ __launch_bounds__(256) void rotate_kernel(
    const float* __restrict__ x, const float* __restrict__ s1,
    const float* __restrict__ s2, u32* __restrict__ rx) {
    int gid  = blockIdx.x * 256 + threadIdx.x;
    int grp  = gid >> 6;
    int lane = gid & 63;

    const float2* xp = (const float2*)(x + (size_t)grp * GSZ);
    float2 xv  = xp[lane];
    float2 s1v = ((const float2*)s1)[lane];
    float2 s2v = ((const float2*)s2)[lane];

    float e0 = xv.x * s1v.x;
    float e1 = xv.y * s1v.y;
    {
        float a = e0 + e1, b = e0 - e1;
        e0 = a; e1 = b;
    }
    #pragma unroll
    for (int hb = 1; hb <= 32; hb <<= 1) {
        float t0 = __shfl_xor(e0, hb, 64);
        float t1 = __shfl_xor(e1, hb, 64);
        bool up = (lane & hb) != 0;
        e0 = up ? (t0 - e0) : (e0 + t0);
        e1 = up ? (t1 - e1) : (e1 + t1);
    }
    const float inv = 0.08838834764831845f;   // 1/sqrt(128)
    u32 lo = f2bf(e0 * s2v.x * inv);
    u32 hi = f2bf(e1 * s2v.y * inv);
    rx[gid] = lo | (hi << 16);
}

// ---------------------------------------------------------------------------
// Kernel 2: dequantize packed 3-bit -> wq bf16 [O][I]. (unchanged, BW-bound)
// ---------------------------------------------------------------------------
__device__ __forceinline__ float cent3(int i) {
    int m3 = (i >= 4) ? (i - 4) : (3 - i);
    float mag = (m3 >= 2) ? ((m3 == 3) ? 2.1519f : 1.3439f)
                          : ((m3 == 1) ? 0.756f  : 0.2451f);
    return (i >= 4) ? mag : -mag;
}

__global__ __launch_bounds__(256) void dequant_kernel(
    const u32* __restrict__ p32, const float* __restrict__ norms,
    u16* __restrict__ wq) {
    int u = blockIdx.x * 256 + threadIdx.x;
    int g_idx = u >> 2;

    float scale = norms[g_idx] * 0.08838834764831845f;

    u32 w0 = p32[(size_t)u * 3 + 0];
    u32 w1 = p32[(size_t)u * 3 + 1];
    u32 w2 = p32[(size_t)u * 3 + 2];

    u32 tri[4];
    if (((w0 | w1 | w2) & 0xFFFFFF00u) == 0u) {
        const u32* pi = p32 + (size_t)u * 12;
        u32 b[12];
        #pragma unroll
        for (int k = 0; k < 12; ++k) b[k] = pi[k];
        #pragma unroll
        for (int t = 0; t < 4; ++t)
            tri[t] = b[3*t] | (b[3*t+1] << 8) | (b[3*t+2] << 16);
    } else {
        tri[0] = w0 & 0xFFFFFFu;
        tri[1] = (w0 >> 24) | ((w1 & 0xFFFFu) << 8);
        tri[2] = (w1 >> 16) | ((w2 & 0xFFu) << 16);
        tri[3] = w2 >> 8;
    }

    u32 ow[16];
    #pragma unroll
    for (int t = 0; t < 4; ++t) {
        u32 v = tri[t];
        #pragma unroll
        for (int k = 0; k < 4; ++k) {
            int i0 = (int)((v >> (6*k))     & 7u);
            int i1 = (int)((v >> (6*k + 3)) & 7u);
            u32 lo = f2bf(cent3(i0) * scale);
            u32 hi = f2bf(cent3(i1) * scale);
            ow[t*4 + k] = lo | (hi << 16);
        }
    }
    u32* op = (u32*)(wq + (size_t)u * 32);
    #pragma unroll
    for (int k = 0; k < 16; ++k) op[k] = ow[k];
}

// ---------------------------------------------------------------------------
// Shared: async half-tile staging (64 rows x 64 cols bf16)
// ---------------------------------------------------------------------------
__device__ __forceinline__ void stage_half(const u16* g, char* ldst, int rowOff, int tt) {
    __builtin_amdgcn_global_load_lds(CAST_G(g + (size_t)rowOff * GK + tt * 64),
                                     CAST_L(ldst), 16, 0, 0);
    __builtin_amdgcn_global_load_lds(CAST_G(g + (size_t)(rowOff + 64) * GK + tt * 64),
                                     CAST_L(ldst + 8192), 16, 0, 0);
}

// ---------------------------------------------------------------------------
// Big path: 256x256 tile, BK=64, 4 phases/K-tile, 2-deep 128 KiB LDS,
// counted vmcnt(6), T2 both-sides XOR swizzle, T5 setprio. (r2/r6-verified)
// ---------------------------------------------------------------------------
template<int BUF>
__device__ __forceinline__ void ktile4(int t, char* lds,
                                       const u16* gA, const u16* gB,
                                       int sB, int aBase, int bBase, int sw0, int sw1,
                                       f32x4 (&acc)[8][4]) {
    const int AB  = BUF * 32768;
    const int BB  = 65536 + BUF * 32768;
    const int BBo = 65536 + (BUF ^ 1) * 32768;

    bf16x8 aF[4][2], b0F[2][2], b1F[2][2];
    bool s1 = (t < 63), s2 = (t < 62);

    // ---- phase 1: quadrant (mh0, nh0)
    #pragma unroll
    for (int mj = 0; mj < 4; ++mj) {
        aF[mj][0] = *(const bf16x8*)(lds + AB + aBase + mj * 4096 + sw0);
        aF[mj][1] = *(const bf16x8*)(lds + AB + aBase + mj * 4096 + sw1);
    }
    #pragma unroll
    for (int nj = 0; nj < 2; ++nj) {
        b0F[nj][0] = *(const bf16x8*)(lds + BB + bBase + nj * 8192 + sw0);
        b0F[nj][1] = *(const bf16x8*)(lds + BB + bBase + nj * 8192 + sw1);
    }
    if (s1) stage_half(gB, lds + BBo + 16384 + sB, 128, t + 1);   // (t+1) B1
    BAR(); SCHED0();
    __builtin_amdgcn_s_setprio(1);
    #pragma unroll
    for (int mj = 0; mj < 4; ++mj)
        #pragma unroll
        for (int nj = 0; nj < 2; ++nj)
            #pragma unroll
            for (int kk = 0; kk < 2; ++kk)
                acc[mj][nj] = __builtin_amdgcn_mfma_f32_16x16x32_bf16(
                    aF[mj][kk], b0F[nj][kk], acc[mj][nj], 0, 0, 0);
    __builtin_amdgcn_s_setprio(0);
    BAR();

    // ---- phase 2: (mh0, nh1)
    #pragma unroll
    for (int nj = 0; nj < 2; ++nj) {
        b1F[nj][0] = *(const bf16x8*)(lds + BB + 16384 + bBase + nj * 8192 + sw0);
        b1F[nj][1] = *(const bf16x8*)(lds + BB + 16384 + bBase + nj * 8192 + sw1);
    }
    if (s2) stage_half(gA, lds + AB + sB, 0, t + 2);              // (t+2) A0
    BAR(); SCHED0();
    __builtin_amdgcn_s_setprio(1);
    #pragma unroll
    for (int mj = 0; mj < 4; ++mj)
        #pragma unroll
        for (int nj = 0; nj < 2; ++nj)
            #pragma unroll
            for (int kk = 0; kk < 2; ++kk)
                acc[mj][2 + nj] = __builtin_amdgcn_mfma_f32_16x16x32_bf16(
                    aF[mj][kk], b1F[nj][kk], acc[mj][2 + nj], 0, 0, 0);
    __builtin_amdgcn_s_setprio(0);
    BAR();

    // ---- phase 3: (mh1, nh0)
    #pragma unroll
    for (int mj = 0; mj < 4; ++mj) {
        aF[mj][0] = *(const bf16x8*)(lds + AB + 16384 + aBase + mj * 4096 + sw0);
        aF[mj][1] = *(const bf16x8*)(lds + AB + 16384 + aBase + mj * 4096 + sw1);
    }
    if (s2) stage_half(gB, lds + BB + sB, 0, t + 2);              // (t+2) B0
    BAR(); SCHED0();
    __builtin_amdgcn_s_setprio(1);
    #pragma unroll
    for (int mj = 0; mj < 4; ++mj)
        #pragma unroll
        for (int nj = 0; nj < 2; ++nj)
            #pragma unroll
            for (int kk = 0; kk < 2; ++kk)
                acc[4 + mj][nj] = __builtin_amdgcn_mfma_f32_16x16x32_bf16(
                    aF[mj][kk], b0F[nj][kk], acc[4 + mj][nj], 0, 0, 0);
    __builtin_amdgcn_s_setprio(0);
    BAR();

    // ---- phase 4: (mh1, nh1)
    if (s2) stage_half(gA, lds + AB + 16384 + sB, 128, t + 2);    // (t+2) A1
    BAR(); SCHED0();
    __builtin_amdgcn_s_setprio(1);
    #pragma unroll
    for (int mj = 0; mj < 4; ++mj)
        #pragma unroll
        for (int nj = 0; nj < 2; ++nj)
            #pragma unroll
            for (int kk = 0; kk < 2; ++kk)
                acc[4 + mj][2 + nj] = __builtin_amdgcn_mfma_f32_16x16x32_bf16(
                    aF[mj][kk], b1F[nj][kk], acc[4 + mj][2 + nj], 0, 0, 0);
    __builtin_amdgcn_s_setprio(0);
    if (s2) { asm volatile("s_waitcnt vmcnt(6)" ::: "memory"); }
    else    { asm volatile("s_waitcnt vmcnt(0)" ::: "memory"); }
    BAR();
}

__device__ __forceinline__ void gemm_big(int tau, int tid, char* lds,
                                         const u16* A, const u16* Bw, float* C) {
    int lane = tid & 63;
    int wv   = tid >> 6;
    int wr   = wv >> 2;
    int wc   = wv & 3;

    int m0 = (tau & 7) * 256;        // XCD x owns A panel x (L2-resident)
    int n0 = (tau >> 3) * 256;

    int srow = tid >> 3;
    int c16  = (tid & 7) ^ (srow & 7);
    const u16* gA = A  + (size_t)(m0 + srow) * GK + c16 * 8;
    const u16* gB = Bw + (size_t)(n0 + srow) * GK + c16 * 8;
    int sB = wv * 1024;

    int aBase = (wr * 16 + (lane & 15)) * 128;
    int bBase = (wc * 16 + (lane & 15)) * 128;
    int sw0 = (((lane >> 4))     ^ (lane & 7)) << 4;
    int sw1 = (((lane >> 4) + 4) ^ (lane & 7)) << 4;

    f32x4 acc[8][4] = {};

    stage_half(gA, lds + sB,                 0,   0);
    stage_half(gB, lds + 65536 + sB,         0,   0);
    stage_half(gA, lds + 16384 + sB,         128, 0);
    stage_half(gB, lds + 65536 + 16384 + sB, 128, 0);
    stage_half(gA, lds + 32768 + sB,         0,   1);
    stage_half(gB, lds + 65536 + 32768 + sB, 0,   1);
    stage_half(gA, lds + 32768 + 16384 + sB, 128, 1);
    asm volatile("s_waitcnt vmcnt(6)" ::: "memory");
    BAR();

    for (int tt = 0; tt < 64; tt += 2) {
        ktile4<0>(tt,     lds, gA, gB, sB, aBase, bBase, sw0, sw1, acc);
        ktile4<1>(tt + 1, lds, gA, gB, sB, aBase, bBase, sw0, sw1, acc);
    }

    int cr = (lane >> 4) * 4;
    int cc = lane & 15;
    #pragma unroll
    for (int mh = 0; mh < 2; ++mh)
        #pragma unroll
        for (int mj = 0; mj < 4; ++mj)
            #pragma unroll
            for (int nh = 0; nh < 2; ++nh)
                #pragma unroll
                for (int nj = 0; nj < 2; ++nj) {
                    float* cp = C + (size_t)(m0 + mh * 128 + wr * 16 + mj * 32 + cr) * GN
                                  + (n0 + nh * 128 + wc * 16 + nj * 64 + cc);
                    #pragma unroll
                    for (int j = 0; j < 4; ++j)
                        __builtin_nontemporal_store(acc[mh * 4 + mj][nh * 2 + nj][j],
                                                    cp + (size_t)j * GN);
                }
}

// ---------------------------------------------------------------------------
// Tail path: 128x256 tile, full-K, 3-deep 144 KiB LDS, 2 phases/K-tile,
// vmcnt(6). (r4/r6-verified)
// ---------------------------------------------------------------------------
template<int BUF>
__device__ __forceinline__ void ktile2(int t, char* lds,
                                       const u16* gA, const u16* gB,
                                       int sB, int aBase, int bBase, int sw0, int sw1,
                                       f32x4 (&acc)[4][4]) {
    const int AB  = BUF * 16384;
    const int BB  = 49152 + BUF * 32768;
    const int NB  = (BUF + 2 >= 3) ? (BUF - 1) : (BUF + 2);
    const int ABn = NB * 16384;
    const int BBn = 49152 + NB * 32768;

    bf16x8 aF[4][2], bF[2][2];
    bool s2 = (t < 62);

    // ---- phase 1: nj = 0,1
    #pragma unroll
    for (int mj = 0; mj < 4; ++mj) {
        aF[mj][0] = *(const bf16x8*)(lds + AB + aBase + mj * 4096 + sw0);
        aF[mj][1] = *(const bf16x8*)(lds + AB + aBase + mj * 4096 + sw1);
    }
    #pragma unroll
    for (int nj = 0; nj < 2; ++nj) {
        bF[nj][0] = *(const bf16x8*)(lds + BB + bBase + nj * 8192 + sw0);
        bF[nj][1] = *(const bf16x8*)(lds + BB + bBase + nj * 8192 + sw1);
    }
    if (s2) {
        stage_half(gA, lds + ABn + sB, 0, t + 2);                 // A(t+2)
        stage_half(gB, lds + BBn + sB, 0, t + 2);                 // B0(t+2)
    }
    BAR(); SCHED0();
    __builtin_amdgcn_s_setprio(1);
    #pragma unroll
    for (int mj = 0; mj < 4; ++mj)
        #pragma unroll
        for (int nj = 0; nj < 2; ++nj)
            #pragma unroll
            for (int kk = 0; kk < 2; ++kk)
                acc[mj][nj] = __builtin_amdgcn_mfma_f32_16x16x32_bf16(
                    aF[mj][kk], bF[nj][kk], acc[mj][nj], 0, 0, 0);
    __builtin_amdgcn_s_setprio(0);
    BAR();

    // ---- phase 2: nj = 2,3
    #pragma unroll
    for (int nj = 0; nj < 2; ++nj) {
        bF[nj][0] = *(const bf16x8*)(lds + BB + 16384 + bBase + nj * 8192 + sw0);
        bF[nj][1] = *(const bf16x8*)(lds + BB + 16384 + bBase + nj * 8192 + sw1);
    }
    if (s2) stage_half(gB, lds + BBn + 16384 + sB, 128, t + 2);   // B1(t+2)
    BAR(); SCHED0();
    __builtin_amdgcn_s_setprio(1);
    #pragma unroll
    for (int mj = 0; mj < 4; ++mj)
        #pragma unroll
        for (int nj = 0; nj < 2; ++nj)
            #pragma unroll
            for (int kk = 0; kk < 2; ++kk)
                acc[mj][2 + nj] = __builtin_amdgcn_mfma_f32_16x16x32_bf16(
                    aF[mj][kk], bF[nj][kk], acc[mj][2 + nj], 0, 0, 0);
    __builtin_amdgcn_s_setprio(0);
    if (s2) { asm volatile("s_waitcnt vmcnt(6)" ::: "memory"); }
    else    { asm volatile("s_waitcnt vmcnt(0)" ::: "memory"); }
    BAR();
}

__device__ __forceinline__ void gemm_tail(int bid, int tid, char* lds,
                                          const u16* A, const u16* Bw, float* C) {
    int lane = tid & 63;
    int wv   = tid >> 6;
    int wr   = wv >> 2;
    int wc   = wv & 3;

    int swz = (bid & 7) * 22 + (bid >> 3);     // 176 = 8 * 22
    int nt  = swz >> 4;                        // 0..10
    int mh  = swz & 15;                        // 0..15
    int m0  = mh * 128;
    int n0  = 8192 + nt * 256;

    int srow = tid >> 3;
    int c16  = (tid & 7) ^ (srow & 7);
    const u16* gA = A  + (size_t)(m0 + srow) * GK + c16 * 8;
    const u16* gB = Bw + (size_t)(n0 + srow) * GK + c16 * 8;
    int sB = wv * 1024;

    int aBase = (wr * 16 + (lane & 15)) * 128;
    int bBase = (wc * 16 + (lane & 15)) * 128;
    int sw0 = (((lane >> 4))     ^ (lane & 7)) << 4;
    int sw1 = (((lane >> 4) + 4) ^ (lane & 7)) << 4;

    f32x4 acc[4][4] = {};

    stage_half(gA, lds + sB,                 0,   0);
    stage_half(gB, lds + 49152 + sB,         0,   0);
    stage_half(gB, lds + 49152 + 16384 + sB, 128, 0);
    stage_half(gA, lds + 16384 + sB,         0,   1);
    stage_half(gB, lds + 81920 + sB,         0,   1);
    stage_half(gB, lds + 81920 + 16384 + sB, 128, 1);
    asm volatile("s_waitcnt vmcnt(6)" ::: "memory");
    BAR();

    for (int tt = 0; tt < 63; tt += 3) {
        ktile2<0>(tt,     lds, gA, gB, sB, aBase, bBase, sw0, sw1, acc);
        ktile2<1>(tt + 1, lds, gA, gB, sB, aBase, bBase, sw0, sw1, acc);
        ktile2<2>(tt + 2, lds, gA, gB, sB, aBase, bBase, sw0, sw1, acc);
    }
    ktile2<0>(63, lds, gA, gB, sB, aBase, bBase, sw0, sw1, acc);

    int cr = (lane >> 4) * 4;
    int cc = lane & 15;
    #pragma unroll
    for (int mj = 0; mj < 4; ++mj)
        #pragma unroll
        for (int nj = 0; nj < 4; ++nj) {
            float* cp = C + (size_t)(m0 + wr * 16 + mj * 32 + cr) * GN
                          + (n0 + wc * 16 + nj * 64 + cc);
            #pragma unroll
            for (int j = 0; j < 4; ++j)
                __builtin_nontemporal_store(acc[mj][nj][j], cp + (size_t)j * GN);
        }
}

// ---------------------------------------------------------------------------
// Merged GEMM: one 432-block dispatch. Blocks 0..255 = 256x256 full tiles
// (n < 8192), blocks 256..431 = 128x256 full-K tail tiles (n >= 8192).
// Big blocks first (LPT): tail blocks back-fill CUs as bigs retire,
// restoring the r2/r5 staggered-entry regime (per-block 113 us vs 127).
// ---------------------------------------------------------------------------
__global__ __launch_bounds__(512, 1) void gemm_all_kernel(
    const u16* __restrict__ A, const u16* __restrict__ Bw,
    float* __restrict__ C) {
    extern __shared__ char lds[];
    int bid = blockIdx.x;
    if (bid < 256) gemm_big (bid,       threadIdx.x, lds, A, Bw, C);
    else           gemm_tail(bid - 256, threadIdx.x, lds, A, Bw, C);
}

// ---------------------------------------------------------------------------
extern "C" void kernel_launch(void* const* d_in, const int* in_sizes, int n_in,
                              void* d_out, int out_size, void* d_ws, size_t ws_size,
                              hipStream_t stream) {
    const float* x      = (const float*)d_in[0];
    const void*  packed = d_in[1];
    const float* norms  = (const float*)d_in[2];
    const float* s1     = (const float*)d_in[4];
    const float* s2     = (const float*)d_in[5];
    float* out          = (float*)d_out;

    size_t rx_bytes = (size_t)GM * GK * 2;
    size_t wq_bytes = (size_t)GN * GK * 2;
    if (ws_size < rx_bytes + wq_bytes) return;

    u16* rx = (u16*)d_ws;
    u16* wq = rx + (size_t)GM * GK;

    rotate_kernel<<<dim3((GM * NGRP * 64) / 256), dim3(256), 0, stream>>>(
        x, s1, s2, (u32*)rx);

    dequant_kernel<<<dim3((GN * NGRP * 4) / 256), dim3(256), 0, stream>>>(
        (const u32*)packed, norms, wq);

    hipFuncSetAttribute((const void*)gemm_all_kernel,
                        hipFuncAttributeMaxDynamicSharedMemorySize, 147456);
    gemm_all_kernel<<<dim3(432), dim3(512), 147456, stream>>>(rx, wq, out);
}